// Round 5
// baseline (370.444 us; speedup 1.0000x reference)
//
#include <hip/hip_runtime.h>
#include <hip/hip_bf16.h>

#define NROW 384
#define GD   1935
#define GK   1952     // padded gate dim (61*32)
#define DD   300
#define KP   320      // padded o
#define DP   304      // padded p

// workspace offsets (in floats)
#define OFF_XBF  4112      // ushort XP[2][24][61][64][8]  frag-packed gated X
#define OFF_EBT  753680    // ushort EP[20][61][64][8]     frag-packed E^T
#define OFF_FC1B 1066000   // ushort[2][320][320]          fc1 plain
#define OFF_FC3B 1168400   // ushort[10][19][64][8]        fc3 frag-packed (kc-major)
#define OFF_F1B  1217040   // ushort[2][384][320]          gated-GEMM out (plain)
#define OFF_AB   1339920   // float: Ahat plain [384][320] | Bhat packed [24][10][64][8]
#define OFF_CD   1585680   // float: Chat plain [384][320] | Dhat packed [24][10][64][8]

typedef short short8 __attribute__((ext_vector_type(8)));
typedef float floatx4 __attribute__((ext_vector_type(4)));

__device__ inline unsigned short f2bf(float x){
  union { float f; unsigned u; } v; v.f = x;
  unsigned r = v.u + 0x7fffu + ((v.u >> 16) & 1u);
  return (unsigned short)(r >> 16);
}

// ---------------------------------------------------------------------------
// k_cvt_all: every bf16 conversion, 8 elems/thread, frag-packed layouts.
// ---------------------------------------------------------------------------
#define TX  (2*24*61*64)     // 187392
#define TE  (20*61*64)       // 78080
#define TF1 (2*320*40)       // 25600
#define TF3 (190*64)         // 12160
#define TTOT (TX+TE+TF1+TF3) // 303232
__global__ void k_cvt_all(const float* f1, const float* f2, const float* E,
                          const float* g1, const float* g2,
                          const float* fc1w, const float* fc3w, float* ws){
  int t = blockIdx.x * 256 + threadIdx.x;
  unsigned short* xbf = (unsigned short*)(ws + OFF_XBF);
  unsigned short* ebt = (unsigned short*)(ws + OFF_EBT);
  unsigned short* f1b = (unsigned short*)(ws + OFF_FC1B);
  unsigned short* f3b = (unsigned short*)(ws + OFF_FC3B);
  if (t < TX){
    int lane = t & 63;
    int rem  = t >> 6;            // ((z*24+mt)*61+kc)
    int kc = rem % 61;
    int rem2 = rem / 61;
    int mt = rem2 % 24, z = rem2 / 24;
    const float* X = z ? f2 : f1;
    const float* g = z ? g2 : g1;
    int n  = mt*16 + (lane & 15);
    int k0 = kc*32 + (lane >> 4)*8;
    union { unsigned short s[8]; uint4 v; } u;
    #pragma unroll
    for (int e = 0; e < 8; ++e){
      int k = k0 + e;
      float v = 0.f;
      if (k < GD){
        float sg = 1.f / (1.f + expf(-g[k]));
        v = X[n*GD + k] * sg;
      }
      u.s[e] = f2bf(v);
    }
    *(uint4*)&xbf[(size_t)t * 8] = u.v;
  } else if (t < TX + TE){
    int i = t - TX;
    int lane = i & 63;
    int rem = i >> 6;
    int kc = rem % 61, ct = rem / 61;
    int c  = ct*16 + (lane & 15);
    int k0 = kc*32 + (lane >> 4)*8;
    union { unsigned short s[8]; uint4 v; } u;
    #pragma unroll
    for (int e = 0; e < 8; ++e){
      int k = k0 + e;
      float v = (k < GD && c < DD) ? E[k*DD + c] : 0.f;
      u.s[e] = f2bf(v);
    }
    *(uint4*)&ebt[(size_t)i * 8] = u.v;
  } else if (t < TX + TE + TF1){
    int i = t - TX - TE;
    int d8 = i % 40; int o = (i/40) % 320; int z = i / (40*320);
    int d0 = d8*8;
    union { unsigned short s[8]; uint4 v; } u;
    #pragma unroll
    for (int e = 0; e < 8; ++e){
      int d = d0 + e;
      float v = (o < DD && d < DD) ? fc1w[o*(2*DD) + z*DD + d] : 0.f;
      u.s[e] = f2bf(v);
    }
    *(uint4*)&f1b[(size_t)((z*KP + o)*KP + d0)] = u.v;
  } else if (t < TTOT){
    int i = t - TX - TE - TF1;
    int lane = i & 63; int g = i >> 6;   // g = kc*19 + pt
    int pt = g % 19, kc = g / 19;
    int p  = pt*16 + (lane & 15);
    int k0 = kc*32 + (lane >> 4)*8;
    union { unsigned short s[8]; uint4 v; } u;
    #pragma unroll
    for (int e = 0; e < 8; ++e){
      int k = k0 + e;
      float v = (p < DD && k < DD) ? fc3w[p*DD + k] : 0.f;
      u.s[e] = f2bf(v);
    }
    *(uint4*)&f3b[(size_t)i * 8] = u.v;
  }
}

// ---------------------------------------------------------------------------
// gated GEMM: F[z][384][320] = X @ E ; frag-packed inputs
// ---------------------------------------------------------------------------
__global__ __launch_bounds__(256) void k_gg(float* ws){
  int z = blockIdx.y;
  const unsigned short* XP = (const unsigned short*)(ws + OFF_XBF) + (size_t)z*24*61*512;
  const unsigned short* EP = (const unsigned short*)(ws + OFF_EBT);
  unsigned short* out      = (unsigned short*)(ws + OFF_F1B) + z*384*KP;
  int t = threadIdx.x, lane = t & 63;
  int id = blockIdx.x * 4 + (t >> 6);      // 0..479
  int mt = id / 20, ct = id - mt*20;
  int col = lane & 15, quad = lane >> 4;
  const unsigned short* ap = XP + (size_t)mt*61*512 + lane*8;
  const unsigned short* bp = EP + (size_t)ct*61*512 + lane*8;
  floatx4 acc = (floatx4){0.f,0.f,0.f,0.f};
  for (int kc = 0; kc < 61; ++kc){
    short8 a = *(const short8*)(ap + kc*512);
    short8 b = *(const short8*)(bp + kc*512);
    acc = __builtin_amdgcn_mfma_f32_16x16x32_bf16(a, b, acc, 0, 0, 0);
  }
  int c = ct*16 + col;
  #pragma unroll
  for (int r = 0; r < 4; ++r){
    int m = mt*16 + quad*4 + r;
    out[m*KP + c] = (c < DD) ? f2bf(acc[r]) : (unsigned short)0;
  }
}

// ---------------------------------------------------------------------------
// fused semantic + spatial. softmax(wloc) inlined per-thread.
// z=0 slabs (n-indexed) plain; z=1 slabs (m-indexed) frag-packed.
// ---------------------------------------------------------------------------
__global__ __launch_bounds__(256) void k_sesp(const float* fc1b, const float* box1,
                      const float* box2, const float* fc2w, const float* fc2b,
                      const float* wloc, float* ws){
  int z = blockIdx.y;
  float wa = wloc[0], wbv = wloc[1];
  float mm = fmaxf(wa, wbv);
  float ea = expf(wa - mm), eb = expf(wbv - mm);
  float w0 = ea / (ea + eb), w1 = eb / (ea + eb);
  int t = threadIdx.x;
  if (blockIdx.x < 120){
    const unsigned short* F = (const unsigned short*)(ws + OFF_F1B) + z*384*KP;
    const unsigned short* W = (const unsigned short*)(ws + OFF_FC1B) + z*KP*KP;
    int lane = t & 63;
    int id = blockIdx.x * 4 + (t >> 6);    // 0..479
    int rt = id / 20, ot = id - rt*20;
    int col = lane & 15, quad = lane >> 4;
    const unsigned short* ap = F + (rt*16 + col)*KP + quad*8;
    const unsigned short* bp = W + (ot*16 + col)*KP + quad*8;
    floatx4 acc = (floatx4){0.f,0.f,0.f,0.f};
    #pragma unroll
    for (int kc = 0; kc < 10; ++kc){
      short8 a = *(const short8*)(ap + kc*32);
      short8 b = *(const short8*)(bp + kc*32);
      acc = __builtin_amdgcn_mfma_f32_16x16x32_bf16(a, b, acc, 0, 0, 0);
    }
    int o = ot*16 + col;
    if (z == 0){
      float bias = (o < DD) ? fc1b[o] : 0.f;
      float* outp = ws + OFF_AB;
      #pragma unroll
      for (int r = 0; r < 4; ++r){
        int rr = rt*16 + quad*4 + r;
        outp[rr*KP + o] = (o < DD) ? w0 * (acc[r] + bias) : 0.f;
      }
    } else {
      float* BP = ws + OFF_AB + 384*KP;
      int kcs = o >> 5, q_o = (o >> 3) & 3, e = o & 7;
      #pragma unroll
      for (int r = 0; r < 4; ++r){
        int lm = quad*4 + r;
        BP[(rt*10 + kcs)*512 + (q_o*16 + lm)*8 + e] = (o < DD) ? w0 * acc[r] : 0.f;
      }
    }
  } else {
    int tt = (blockIdx.x - 120) * 256 + t;   // 0..122879
    int r = tt / KP, o = tt - r*KP;
    const float* bx = z ? box2 : box1;
    int joff = z ? 5 : 0;
    float v = 0.f;
    if (o < DD){
      const float* b = bx + r * 5;
      const float* wr = fc2w + o * 10 + joff;
      v = b[0]*wr[0] + b[1]*wr[1] + b[2]*wr[2] + b[3]*wr[3] + b[4]*wr[4];
      if (!z) v += fc2b[o];
      v *= w1;
    }
    if (z == 0) ws[OFF_CD + tt] = v;
    else {
      float* DPp = ws + OFF_CD + 384*KP;
      int mt = r >> 4, lm = r & 15, kcs = o >> 5, q_o = (o >> 3) & 3, e = o & 7;
      DPp[(mt*10 + kcs)*512 + (q_o*16 + lm)*8 + e] = v;
    }
  }
}

// ---------------------------------------------------------------------------
// main: out[n][m][p] = sum_o mixed(n,m,o)*fc3[p][o] + fc3b[p]
//  - NON-TEMPORAL output stores (write stream stops thrashing L2)
//  - counted barrier: s_waitcnt lgkmcnt(0) + raw s_barrier + sched_barrier(0)
//    (rule #18 hardening) so next-kc global loads stay in flight
//  - 2-deep build-load pipeline
//  - grid (4,384) x 384thr: block id = n*4+x -> XCD = {x, x+4}; each XCD's
//    working set ~1.2 MB -> L2-resident once stores are non-temporal
// ---------------------------------------------------------------------------
__global__ __launch_bounds__(384, 3) void k_main(const float* fc3b, float* out, const float* ws){
  __shared__ __align__(16) unsigned short wbuf[2][19*512];   // 2 x 19456 B
  const unsigned short* fc3p = (const unsigned short*)(ws + OFF_FC3B);
  int t = threadIdx.x;
  int lane = t & 63, wave = t >> 6;          // wave 0..5
  int col = lane & 15, quad = lane >> 4;
  int n = blockIdx.y;
  int mt = blockIdx.x * 6 + wave;            // 0..23
  const float* Ah = ws + OFF_AB + n * KP;
  const float* Ch = ws + OFF_CD + n * KP;
  const float* BP  = ws + OFF_AB + 384*KP + (size_t)mt*10*512 + lane*8;
  const float* DPp = ws + OFF_CD + 384*KP + (size_t)mt*10*512 + lane*8;

  floatx4 acc[19];
  #pragma unroll
  for (int i = 0; i < 19; ++i) acc[i] = (floatx4){0.f,0.f,0.f,0.f};

  // stage kc=0 weights (1216 uint4, 384 threads)
  {
    const uint4* src = (const uint4*)fc3p;
    uint4* dst = (uint4*)&wbuf[0][0];
    dst[t] = src[t]; dst[t + 384] = src[t + 384]; dst[t + 768] = src[t + 768];
    if (t < 64) dst[t + 1152] = src[t + 1152];
  }
  // preload kc=0 build operands
  float4 na0 = *(const float4*)(Ah + quad*8);
  float4 na1 = *(const float4*)(Ah + quad*8 + 4);
  float4 nc0 = *(const float4*)(Ch + quad*8);
  float4 nc1 = *(const float4*)(Ch + quad*8 + 4);
  float4 nb0 = *(const float4*)(BP);
  float4 nb1 = *(const float4*)(BP + 4);
  float4 nd0 = *(const float4*)(DPp);
  float4 nd1 = *(const float4*)(DPp + 4);
  __syncthreads();   // initial full drain (once)

  for (int kc = 0; kc < 10; ++kc){
    bool pre = (kc < 9);
    // weight prefetch for kc+1 — issued FIRST so the ds_write's vmcnt wait
    // leaves the (later-issued) build loads in flight
    uint4 s0, s1, s2, s3;
    if (pre){
      const uint4* src = (const uint4*)(fc3p + (size_t)(kc+1) * (19*512));
      s0 = src[t]; s1 = src[t + 384]; s2 = src[t + 768];
      if (t < 64) s3 = src[t + 1152];
    }
    // current build operands (loaded last iteration)
    float4 a0=na0, a1=na1, b0=nb0, b1=nb1, c0=nc0, c1=nc1, d0=nd0, d1=nd1;
    // issue next-kc build loads (stay in flight across the barrier)
    if (pre){
      int kb = (kc+1)*32 + quad*8;
      na0 = *(const float4*)(Ah + kb);   na1 = *(const float4*)(Ah + kb + 4);
      nc0 = *(const float4*)(Ch + kb);   nc1 = *(const float4*)(Ch + kb + 4);
      nb0 = *(const float4*)(BP + (kc+1)*512);  nb1 = *(const float4*)(BP + (kc+1)*512 + 4);
      nd0 = *(const float4*)(DPp + (kc+1)*512); nd1 = *(const float4*)(DPp + (kc+1)*512 + 4);
    }
    // build A-frag in registers
    union { unsigned short s[8]; short8 v8; } u;
    u.s[0] = f2bf(fmaxf(a0.x + b0.x, 0.f) + fmaxf(c0.x + d0.x, 0.f));
    u.s[1] = f2bf(fmaxf(a0.y + b0.y, 0.f) + fmaxf(c0.y + d0.y, 0.f));
    u.s[2] = f2bf(fmaxf(a0.z + b0.z, 0.f) + fmaxf(c0.z + d0.z, 0.f));
    u.s[3] = f2bf(fmaxf(a0.w + b0.w, 0.f) + fmaxf(c0.w + d0.w, 0.f));
    u.s[4] = f2bf(fmaxf(a1.x + b1.x, 0.f) + fmaxf(c1.x + d1.x, 0.f));
    u.s[5] = f2bf(fmaxf(a1.y + b1.y, 0.f) + fmaxf(c1.y + d1.y, 0.f));
    u.s[6] = f2bf(fmaxf(a1.z + b1.z, 0.f) + fmaxf(c1.z + d1.z, 0.f));
    u.s[7] = f2bf(fmaxf(a1.w + b1.w, 0.f) + fmaxf(c1.w + d1.w, 0.f));
    short8 af = u.v8;
    const unsigned short* wb = wbuf[kc & 1];
    #pragma unroll
    for (int pt = 0; pt < 19; ++pt){
      short8 bf = *(const short8*)(wb + pt*512 + lane*8);
      acc[pt] = __builtin_amdgcn_mfma_f32_16x16x32_bf16(af, bf, acc[pt], 0, 0, 0);
    }
    // write next weight slice, then barrier WITHOUT vmcnt drain
    if (pre){
      uint4* dst = (uint4*)&wbuf[(kc + 1) & 1][0];
      dst[t] = s0; dst[t + 384] = s1; dst[t + 768] = s2;
      if (t < 64) dst[t + 1152] = s3;
      asm volatile("s_waitcnt lgkmcnt(0)" ::: "memory");
      __builtin_amdgcn_s_barrier();
      __builtin_amdgcn_sched_barrier(0);   // rule #18: pin phase boundary
    }
  }

  #pragma unroll
  for (int pt = 0; pt < 19; ++pt){
    int p = pt*16 + col;
    if (p < DD){
      float bias = fc3b[p];
      #pragma unroll
      for (int r = 0; r < 4; ++r){
        int m = mt*16 + quad*4 + r;
        __builtin_nontemporal_store(acc[pt][r] + bias,
                                    &out[((size_t)n * NROW + m) * DD + p]);
      }
    }
  }
}

extern "C" void kernel_launch(void* const* d_in, const int* in_sizes, int n_in,
                              void* d_out, int out_size, void* d_ws, size_t ws_size,
                              hipStream_t stream) {
  const float* feature1 = (const float*)d_in[0];
  const float* box1     = (const float*)d_in[1];
  const float* feature2 = (const float*)d_in[2];
  const float* box2     = (const float*)d_in[3];
  const float* E        = (const float*)d_in[4];
  const float* gate1    = (const float*)d_in[5];
  const float* gate2    = (const float*)d_in[6];
  const float* wloc     = (const float*)d_in[7];
  const float* fc1w     = (const float*)d_in[8];
  const float* fc1b     = (const float*)d_in[9];
  const float* fc2w     = (const float*)d_in[10];
  const float* fc2b     = (const float*)d_in[11];
  const float* fc3w     = (const float*)d_in[12];
  const float* fc3b     = (const float*)d_in[13];
  float* out = (float*)d_out;
  float* ws  = (float*)d_ws;

  hipLaunchKernelGGL(k_cvt_all, dim3((TTOT + 255)/256), dim3(256), 0, stream,
                     feature1, feature2, E, gate1, gate2, fc1w, fc3w, ws);
  hipLaunchKernelGGL(k_gg, dim3(120, 2), dim3(256), 0, stream, ws);
  hipLaunchKernelGGL(k_sesp, dim3(600, 2), dim3(256), 0, stream,
                     fc1b, box1, box2, fc2w, fc2b, wloc, ws);
  hipLaunchKernelGGL(k_main, dim3(4, NROW), dim3(384), 0, stream, fc3b, out, ws);
}